// Round 1
// baseline (159.370 us; speedup 1.0000x reference)
//
#include <hip/hip_runtime.h>

// y[n,f] = sum_p w_table[widx[n],p] * pool[idx[n,p],f]
// pool = concat(values0, values1) along rows.
// N=500000, P=16, F=32, M=200000, K=10000. All f32; idx/widx arrive as int32.

#define PP 16
#define FF 32

__global__ __launch_bounds__(256) void linear_gather_kernel(
    const float* __restrict__ values0,
    const float* __restrict__ values1,
    const float* __restrict__ w_table,
    const int*   __restrict__ idx,
    const int*   __restrict__ widx,
    float*       __restrict__ out,
    int N, int M)
{
    int t = blockIdx.x * blockDim.x + threadIdx.x;
    int n  = t >> 3;   // 8 lanes per neuron
    int f4 = t & 7;    // which float4 of the 32-float row
    if (n >= N) return;

    const float* wrow = w_table + (long)widx[n] * PP;
    const int*   irow = idx + (long)n * PP;

    float4 acc = make_float4(0.f, 0.f, 0.f, 0.f);
#pragma unroll
    for (int p = 0; p < PP; ++p) {
        int   i = irow[p];                 // same addr across the 8 lanes -> broadcast
        float w = wrow[p];                 // same addr across the 8 lanes -> broadcast
        const float* src = (i < M) ? (values0 + (long)i * FF)
                                   : (values1 + (long)(i - M) * FF);
        float4 v = *reinterpret_cast<const float4*>(src + f4 * 4);
        acc.x += w * v.x;
        acc.y += w * v.y;
        acc.z += w * v.z;
        acc.w += w * v.w;
    }
    reinterpret_cast<float4*>(out)[(long)n * 8 + f4] = acc;
}

extern "C" void kernel_launch(void* const* d_in, const int* in_sizes, int n_in,
                              void* d_out, int out_size, void* d_ws, size_t ws_size,
                              hipStream_t stream) {
    const float* values0 = (const float*)d_in[0];
    const float* values1 = (const float*)d_in[1];
    const float* w_table = (const float*)d_in[2];
    const int*   idx     = (const int*)d_in[3];
    const int*   widx    = (const int*)d_in[4];
    float*       out     = (float*)d_out;

    const int N = in_sizes[4];          // widx has N elements
    const int M = in_sizes[0] / FF;     // values0 rows

    long total_threads = (long)N * 8;
    int  block = 256;
    int  grid  = (int)((total_threads + block - 1) / block);

    linear_gather_kernel<<<grid, block, 0, stream>>>(
        values0, values1, w_table, idx, widx, out, N, M);
}